// Round 2
// baseline (399.184 us; speedup 1.0000x reference)
//
#include <hip/hip_runtime.h>
#include <hip/hip_bf16.h>
#include <math.h>
#include <stdint.h>

typedef __bf16 bf16_t;
typedef __bf16 bf16x4 __attribute__((ext_vector_type(4)));
typedef __bf16 bf16x8 __attribute__((ext_vector_type(8)));
typedef float  f32x4  __attribute__((ext_vector_type(4)));

#define BATCH   4096
#define DM      1024
#define DFF     2048
#define NTILES  8
#define MAXXB   40   // max compacted x-blocks: 32 + 7 partials

__device__ __forceinline__ float gelu_exact(float x) {
    return 0.5f * x * (1.0f + erff(x * 0.70710678118654752440f));
}

__device__ __forceinline__ void async_ld16(const bf16_t* g, bf16_t* l) {
    __builtin_amdgcn_global_load_lds(
        (const __attribute__((address_space(1))) void*)g,
        (__attribute__((address_space(3))) void*)l, 16, 0, 0);
}

__device__ __forceinline__ f32x4 mfma16(bf16x8 a, bf16x8 b, f32x4 c) {
    return __builtin_amdgcn_mfma_f32_16x16x32_bf16(a, b, c, 0, 0, 0);
}

// ---------------- fused prep: x hi/lo split + 4 weight transposes ----------------
// (unchanged — isolating the GEMM pipeline delta this round)
template<bool LO>
__device__ void tconv64_body(const float* __restrict__ src, bf16_t* __restrict__ outh,
                             bf16_t* __restrict__ outl, int K, int N, int kt, int nt,
                             float4* t /* 64*16 float4 = 16KB */) {
    const int tid = threadIdx.x;
    const int k0 = kt * 64, n0 = nt * 64;
#pragma unroll
    for (int p = 0; p < 4; ++p) {
        int row = p * 16 + (tid >> 4);
        int c = tid & 15;
        float4 v = *(const float4*)(src + (size_t)(k0 + row) * N + n0 + c * 4);
        t[row * 16 + (c ^ ((row >> 2) & 15))] = v;
    }
    __syncthreads();
    const int n = tid >> 2, b = tid & 3;
    const float* tf = (const float*)t;
    float v[16];
#pragma unroll
    for (int i = 0; i < 16; ++i) {
        int k = 16 * b + i;
        int f4 = k * 16 + ((n >> 2) ^ ((k >> 2) & 15));
        v[i] = tf[f4 * 4 + (n & 3)];
    }
    bf16x8 h0, h1;
#pragma unroll
    for (int i = 0; i < 8; ++i) { h0[i] = (bf16_t)v[i]; h1[i] = (bf16_t)v[8 + i]; }
    size_t oi = (size_t)(n0 + n) * K + k0 + 16 * b;
    *(bf16x8*)(outh + oi) = h0;
    *(bf16x8*)(outh + oi + 8) = h1;
    if constexpr (LO) {
        bf16x8 l0, l1;
#pragma unroll
        for (int i = 0; i < 8; ++i) {
            l0[i] = (bf16_t)(v[i] - (float)h0[i]);
            l1[i] = (bf16_t)(v[8 + i] - (float)h1[i]);
        }
        *(bf16x8*)(outl + oi) = l0;
        *(bf16x8*)(outl + oi + 8) = l1;
    }
}

#define NCVT2 2048
#define NSQ64 256
#define NW1   4096
#define NW2   4096
#define PREP_GRID (NCVT2 + NSQ64 + NSQ64 + NW1 + NW2)

__global__ __launch_bounds__(256) void prep_kernel(
    const float* __restrict__ x, const float* __restrict__ Wr1, const float* __restrict__ Wo,
    const float* __restrict__ W1, const float* __restrict__ W2,
    bf16_t* __restrict__ xh, bf16_t* __restrict__ xl,
    bf16_t* __restrict__ Wr1h, bf16_t* __restrict__ Wr1l, bf16_t* __restrict__ Wot,
    bf16_t* __restrict__ W1t, bf16_t* __restrict__ W2t) {
    __shared__ float4 t[64 * 16];
    int b = blockIdx.x;
    if (b < NCVT2) {
        size_t i = (size_t)b * 256 + threadIdx.x;
        const float4* x4 = (const float4*)x;
        float4 v0 = x4[2 * i], v1 = x4[2 * i + 1];
        float f[8] = {v0.x, v0.y, v0.z, v0.w, v1.x, v1.y, v1.z, v1.w};
        bf16x8 h, l;
#pragma unroll
        for (int j = 0; j < 8; ++j) { h[j] = (bf16_t)f[j]; l[j] = (bf16_t)(f[j] - (float)h[j]); }
        *(bf16x8*)(xh + i * 8) = h;
        *(bf16x8*)(xl + i * 8) = l;
        return;
    }
    b -= NCVT2;
    if (b < NSQ64) { tconv64_body<true >(Wr1, Wr1h, Wr1l, DM, DM, b >> 4, b & 15, t); return; }
    b -= NSQ64;
    if (b < NSQ64) { tconv64_body<false>(Wo, Wot, nullptr, DM, DM, b >> 4, b & 15, t); return; }
    b -= NSQ64;
    if (b < NW1) {
        int mat = b >> 9, r = b & 511;
        size_t off = (size_t)mat * DM * DFF;
        tconv64_body<false>(W1 + off, W1t + off, nullptr, DM, DFF, r >> 5, r & 31, t);
        return;
    }
    b -= NW1;
    {
        int mat = b >> 9, r = b & 511;
        size_t off = (size_t)mat * DM * DFF;
        tconv64_body<false>(W2 + off, W2t + off, nullptr, DFF, DM, r >> 4, r & 15, t);
    }
}

// ---------------- GEMM: C[M,N] = A[M,K] @ Bt[N,K]^T (+bias, opt gelu) ----------------
// 128x128 tile, BK=32, 8 waves (2x4: wave tile 64x32), global_load_lds width-16.
// T3+T4: 3-buffer LDS pipeline, counted s_waitcnt vmcnt(N) (never 0 in steady
// state) + raw s_barrier. Tile t+2 is staged while tile t computes; each staged
// load gets ~2 iterations of flight time. Buffer lifetime: buf(t+2)==buf(t-1),
// whose LDS reads completed before every wave reached barrier(t).
// SPLIT: hi matrices via the same pipeline; LO operands are NOT staged in LDS —
// they are register-loaded directly from global (L2/L3-resident), software-
// pipelined one iteration ahead. vmcnt counts re-derived: steady wait = 2
// (non-split: st(t+1) in flight) or 8 (split: st(t+1)+lo(t) in flight).
template<bool SPLIT, bool GATHER, bool GELU, bool SCATTER, bool OUTF32>
__global__ __launch_bounds__(512) void gemm_kernel(
    const bf16_t* __restrict__ A, const bf16_t* __restrict__ Alo,
    const bf16_t* __restrict__ Bt, const bf16_t* __restrict__ Btlo,
    const float* __restrict__ bias,
    float* __restrict__ outF, bf16_t* __restrict__ outB,
    const int* __restrict__ perm, const int* __restrict__ counts,
    int M, int N, int K) {
    int tile = 0, rb, cnt = M;
    const int* permT = nullptr;
    if constexpr (GATHER) {
        int xb = blockIdx.x, t = 0, c = 0;
        while (t < NTILES) {
            c = counts[t];
            int nbk = (c + 127) >> 7;
            if (xb < nbk) break;
            xb -= nbk; ++t;
        }
        if (t == NTILES) return;          // beyond total routed blocks (uniform)
        tile = t;
        rb = xb * 128;
        cnt = c;
        permT = perm + tile * BATCH;
    } else {
        rb = blockIdx.x * 128;
    }
    Bt   += (size_t)tile * K * N;
    if constexpr (SPLIT) Btlo += (size_t)tile * K * N;
    bias += (size_t)tile * N;

    constexpr int BUF = 128 * 32;          // elements per buffer (8KB)
    __shared__ __align__(16) bf16_t As[3 * BUF];   // 24KB
    __shared__ __align__(16) bf16_t Bs[3 * BUF];   // 24KB

    const int lane = threadIdx.x & 63;
    const int wave = threadIdx.x >> 6;     // 0..7
    const int wm = wave & 1, wn = wave >> 1;   // 2 x 4 wave grid
    const int nb = blockIdx.y * 128;

    // staging source offsets (one 16B lane-load per matrix per K-step)
    const int srow = lane >> 2;                       // 0..15 within wave's 16-row seg
    const int scol = ((lane & 3) ^ (srow & 3)) * 8;   // swizzled k-chunk (elements)
    const int row = wave * 16 + srow;                 // 0..127
    int arow;
    if constexpr (GATHER) {
        int pos = rb + row;
        if (pos > cnt - 1) pos = cnt - 1;
        arow = permT[pos];
    } else {
        arow = rb + row;
    }
    const size_t aoff = (size_t)arow * K + scol;
    const size_t boff = (size_t)(nb + row) * K + scol;

    f32x4 acc[4][2];
#pragma unroll
    for (int i = 0; i < 4; ++i)
#pragma unroll
        for (int j = 0; j < 2; ++j) acc[i][j] = (f32x4){0.f, 0.f, 0.f, 0.f};

    const int lr = lane & 15, lq = lane >> 4;
    const int rdoff = (lr * 4 + (lq ^ (lr & 3))) * 8;

    // SPLIT: direct-global lo-fragment addresses (frag row = subtile*16+lr, k-chunk = lq)
    size_t aloOff[4], bloOff[2];
    if constexpr (SPLIT) {
#pragma unroll
        for (int i = 0; i < 4; ++i)
            aloOff[i] = (size_t)(rb + (wm * 4 + i) * 16 + lr) * K + lq * 8;
#pragma unroll
        for (int j = 0; j < 2; ++j)
            bloOff[j] = (size_t)(nb + (wn * 2 + j) * 16 + lr) * K + lq * 8;
    }

    auto stage = [&](int k0, int buf) {
        async_ld16(A  + aoff + k0, &As[buf * BUF + wave * 512]);
        async_ld16(Bt + boff + k0, &Bs[buf * BUF + wave * 512]);
    };

    auto loadLo = [&](int k0, bf16x8* a, bf16x8* b) {
#pragma unroll
        for (int i = 0; i < 4; ++i) a[i] = *(const bf16x8*)(Alo  + aloOff[i] + k0);
#pragma unroll
        for (int j = 0; j < 2; ++j) b[j] = *(const bf16x8*)(Btlo + bloOff[j] + k0);
    };

    auto compute = [&](int cur, const bf16x8* afl, const bf16x8* bfl) {
        bf16x8 af[4], bfr[2];
#pragma unroll
        for (int i = 0; i < 4; ++i)
            af[i] = *(const bf16x8*)&As[cur * BUF + (wm * 4 + i) * 512 + rdoff];
#pragma unroll
        for (int j = 0; j < 2; ++j)
            bfr[j] = *(const bf16x8*)&Bs[cur * BUF + (wn * 2 + j) * 512 + rdoff];
        __builtin_amdgcn_s_setprio(1);
        // hi*hi first (no dependence on lo loads)
#pragma unroll
        for (int i = 0; i < 4; ++i)
#pragma unroll
            for (int j = 0; j < 2; ++j)
                acc[i][j] = mfma16(af[i], bfr[j], acc[i][j]);
        if constexpr (SPLIT) {
            // hi*lo cross terms; lo*lo ~1e-6, dropped
#pragma unroll
            for (int i = 0; i < 4; ++i)
#pragma unroll
                for (int j = 0; j < 2; ++j) {
                    acc[i][j] = mfma16(af[i], bfl[j], acc[i][j]);
                    acc[i][j] = mfma16(afl[i], bfr[j], acc[i][j]);
                }
        }
        __builtin_amdgcn_s_setprio(0);
    };

    bf16x8 aflC[4], bflC[2], aflN[4], bflN[2];
    stage(0, 0);
    stage(32, 1);
    if constexpr (SPLIT) loadLo(0, aflN, bflN);   // after stages: keeps vmcnt math uniform

    int bufc = 0;
    for (int k0 = 0; k0 < K; k0 += 32) {
        // counted wait: ensure tile t staged (all waves also did before their barrier)
        if (k0 + 32 < K) {
            if constexpr (SPLIT) asm volatile("s_waitcnt vmcnt(8)" ::: "memory");
            else                 asm volatile("s_waitcnt vmcnt(2)" ::: "memory");
        } else {
            asm volatile("s_waitcnt vmcnt(0)" ::: "memory");
        }
        __builtin_amdgcn_s_barrier();
        int nb3 = bufc + 2; if (nb3 >= 3) nb3 -= 3;
        if (k0 + 64 < K) stage(k0 + 64, nb3);
        if constexpr (SPLIT) {
#pragma unroll
            for (int i = 0; i < 4; ++i) aflC[i] = aflN[i];
#pragma unroll
            for (int j = 0; j < 2; ++j) bflC[j] = bflN[j];
            if (k0 + 32 < K) loadLo(k0 + 32, aflN, bflN);
        }
        __builtin_amdgcn_sched_barrier(0);       // keep stage/lo-issue above the MFMA cluster
        compute(bufc, aflC, bflC);
        if (++bufc == 3) bufc = 0;
    }

    // epilogue: C row = (lane>>4)*4 + reg, col = lane&15 (m89/m91-verified)
#pragma unroll
    for (int i = 0; i < 4; ++i) {
#pragma unroll
        for (int j = 0; j < 2; ++j) {
#pragma unroll
            for (int r = 0; r < 4; ++r) {
                int m = wm * 64 + i * 16 + lq * 4 + r;
                int n = wn * 32 + j * 16 + lr;
                int pos = rb + m;
                if constexpr (GATHER) { if (pos >= cnt) continue; }
                int grow;
                if constexpr (SCATTER) grow = permT[pos];
                else                   grow = pos;
                int gn = nb + n;
                float v = acc[i][j][r] + bias[gn];
                if constexpr (GELU) v = gelu_exact(v);
                if constexpr (OUTF32) outF[(size_t)grow * N + gn] = v;
                else                  outB[(size_t)grow * N + gn] = (bf16_t)v;
            }
        }
    }
}

// ---------------- router layer2 + argmax + routing lists ----------------
// (unchanged from previous round)
__global__ __launch_bounds__(256) void router2_kernel(
    const float* __restrict__ Hr, const float* __restrict__ Wr2, const float* __restrict__ br2,
    float* __restrict__ outLog, float* __restrict__ outIdx,
    int* __restrict__ counts, int* __restrict__ perm) {
    __shared__ float w2s[DM * 9];
    __shared__ int h[NTILES], base[NTILES];
    const int tid = threadIdx.x;
    if (tid < NTILES) h[tid] = 0;
    for (int e = tid; e < DM * 8; e += 256) {
        int k = e >> 3, j = e & 7;
        w2s[k * 9 + j] = Wr2[e];
    }
    __syncthreads();

    const int lane = tid & 63, wave = tid >> 6;
    const int sub = lane >> 4;
    const int lr16 = lane & 15;
    const int row = blockIdx.x * 16 + wave * 4 + sub;

    const float4* Hr4 = (const float4*)Hr;
    float acc[8];
#pragma unroll
    for (int j = 0; j < 8; ++j) acc[j] = 0.f;

#pragma unroll
    for (int i = 0; i < 16; ++i) {
        int f = lr16 + i * 16;
        float4 hv = Hr4[(size_t)row * 256 + f];
        float hx[4] = {hv.x, hv.y, hv.z, hv.w};
        int kbase = f * 4;
#pragma unroll
        for (int d = 0; d < 4; ++d) {
            float xv = hx[d];
            const float* w = &w2s[(kbase + d) * 9];
#pragma unroll
            for (int j = 0; j < 8; ++j) acc[j] += xv * w[j];
        }
    }
#pragma unroll
    for (int off = 8; off; off >>= 1)
#pragma unroll
        for (int j = 0; j < 8; ++j) acc[j] += __shfl_down(acc[j], off);

    int bi = 0, rank = 0;
    if (lr16 == 0) {
        float best = -1e30f;
        float lg[8];
#pragma unroll
        for (int j = 0; j < 8; ++j) {
            float v = (acc[j] + br2[j]) * 2.0f;   // /TEMPERATURE, T=0.5
            lg[j] = v;
            if (v > best) { best = v; bi = j; }   // strict > == first-max (jnp.argmax)
        }
        float4 lo = {lg[0], lg[1], lg[2], lg[3]};
        float4 hi = {lg[4], lg[5], lg[6], lg[7]};
        *(float4*)(outLog + (size_t)row * 8)     = lo;
        *(float4*)(outLog + (size_t)row * 8 + 4) = hi;
        outIdx[row] = (float)bi;
        rank = atomicAdd(&h[bi], 1);
    }
    __syncthreads();
    if (tid < NTILES && h[tid] > 0) base[tid] = atomicAdd(&counts[tid], h[tid]);
    __syncthreads();
    if (lr16 == 0) perm[bi * BATCH + base[bi] + rank] = row;
}

// ---------------- host launch ----------------
extern "C" void kernel_launch(void* const* d_in, const int* in_sizes, int n_in,
                              void* d_out, int out_size, void* d_ws, size_t ws_size,
                              hipStream_t stream) {
    const float* x   = (const float*)d_in[0];
    const float* Wr1 = (const float*)d_in[1];
    const float* br1 = (const float*)d_in[2];
    const float* Wr2 = (const float*)d_in[3];
    const float* br2 = (const float*)d_in[4];
    const float* W1  = (const float*)d_in[5];
    const float* b1  = (const float*)d_in[6];
    const float* W2  = (const float*)d_in[7];
    const float* b2  = (const float*)d_in[8];
    const float* Wo  = (const float*)d_in[9];
    const float* bo  = (const float*)d_in[10];

    char* ws = (char*)d_ws;
    size_t o = 0;
    auto carve = [&](size_t bytes) { char* p = ws + o; o = (o + bytes + 255) & ~(size_t)255; return p; };
    bf16_t* Wr1h = (bf16_t*)carve((size_t)DM * DM * 2);
    bf16_t* Wr1l = (bf16_t*)carve((size_t)DM * DM * 2);
    bf16_t* Wot  = (bf16_t*)carve((size_t)DM * DM * 2);
    bf16_t* W1t  = (bf16_t*)carve((size_t)NTILES * DM * DFF * 2);
    bf16_t* W2t  = (bf16_t*)carve((size_t)NTILES * DM * DFF * 2);
    bf16_t* xh   = (bf16_t*)carve((size_t)BATCH * DM * 2);
    bf16_t* xl   = (bf16_t*)carve((size_t)BATCH * DM * 2);
    bf16_t* H1   = (bf16_t*)carve((size_t)BATCH * DFF * 2);
    bf16_t* sel  = (bf16_t*)carve((size_t)BATCH * DM * 2);
    float*  Hr   = (float*)carve((size_t)BATCH * DM * 4);
    int*    counts = (int*)carve(NTILES * sizeof(int));
    int*    perm   = (int*)carve((size_t)NTILES * BATCH * sizeof(int));

    float* outMain = (float*)d_out;
    float* outIdx  = outMain + (size_t)BATCH * DM;
    float* outLog  = outIdx + BATCH;

    hipMemsetAsync(counts, 0, NTILES * sizeof(int), stream);

    prep_kernel<<<PREP_GRID, 256, 0, stream>>>(x, Wr1, Wo, W1, W2,
                                               xh, xl, Wr1h, Wr1l, Wot, W1t, W2t);

    // router layer 1: Hr = gelu(x @ Wr1 + br1), hi/lo split for fp32-class accuracy
    gemm_kernel<true, false, true, false, true><<<dim3(BATCH / 128, DM / 128, 1), 512, 0, stream>>>(
        xh, xl, Wr1h, Wr1l, br1, Hr, nullptr, nullptr, nullptr, BATCH, DM, DM);

    router2_kernel<<<BATCH / 16, 256, 0, stream>>>(Hr, Wr2, br2, outLog, outIdx, counts, perm);

    // expert layer 1: H1[token] = gelu(x[token] @ W1[t] + b1[t]), gathered+scattered
    gemm_kernel<false, true, true, true, false><<<dim3(MAXXB, DFF / 128, 1), 512, 0, stream>>>(
        xh, nullptr, W1t, nullptr, b1, nullptr, H1, perm, counts, BATCH, DFF, DM);

    // expert layer 2: sel[token] = H1[token] @ W2[t] + b2[t]
    gemm_kernel<false, true, false, true, false><<<dim3(MAXXB, DM / 128, 1), 512, 0, stream>>>(
        H1, nullptr, W2t, nullptr, b2, nullptr, sel, perm, counts, BATCH, DM, DFF);

    // output projection: out = sel @ Wo + bo
    gemm_kernel<false, false, false, false, true><<<dim3(BATCH / 128, DM / 128, 1), 512, 0, stream>>>(
        sel, nullptr, Wot, nullptr, bo, outMain, nullptr, nullptr, nullptr, BATCH, DM, DM);
}

// Round 3
// 371.013 us; speedup vs baseline: 1.0759x; 1.0759x over previous
//
#include <hip/hip_runtime.h>
#include <hip/hip_bf16.h>
#include <math.h>
#include <stdint.h>

typedef __bf16 bf16_t;
typedef __bf16 bf16x4 __attribute__((ext_vector_type(4)));
typedef __bf16 bf16x8 __attribute__((ext_vector_type(8)));
typedef float  f32x4  __attribute__((ext_vector_type(4)));

#define BATCH   4096
#define DM      1024
#define DFF     2048
#define NTILES  8
#define MAXXB   40   // max compacted x-blocks: 32 + 7 partials

__device__ __forceinline__ float gelu_exact(float x) {
    return 0.5f * x * (1.0f + erff(x * 0.70710678118654752440f));
}

__device__ __forceinline__ void async_ld16(const bf16_t* g, bf16_t* l) {
    __builtin_amdgcn_global_load_lds(
        (const __attribute__((address_space(1))) void*)g,
        (__attribute__((address_space(3))) void*)l, 16, 0, 0);
}

__device__ __forceinline__ f32x4 mfma16(bf16x8 a, bf16x8 b, f32x4 c) {
    return __builtin_amdgcn_mfma_f32_16x16x32_bf16(a, b, c, 0, 0, 0);
}

// ---------------- fused prep: x hi/lo split + 4 weight transposes ----------------
// NEW this round: 64x256 slab per block (4 tiles, pipelined). Staging via
// global_load_lds dwordx4 with the f4-XOR swizzle applied to the per-lane
// GLOBAL source column (LDS dest linear, as the HW requires; permutation stays
// within one 256B row segment -> coalescing preserved). Two 16KB buffers
// ping-pong with raw s_barrier + counted vmcnt(4): tile s+1's 4 loads stay in
// flight across the whole phase-2 (LDS read + cvt + store) of tile s.
// Phase-2 math identical to the previous (verified) tconv64_body.
template<bool LO>
__device__ void tslab_body(const float* __restrict__ src, bf16_t* __restrict__ outh,
                           bf16_t* __restrict__ outl, int K, int N, int kt, int nt0,
                           float4* t /* 2 x 64*16 float4 = 32KB */) {
    const int tid = threadIdx.x;
    const int lane = tid & 63, wave = tid >> 6;
    const int k0 = kt * 64;
    const int lrow4 = lane >> 4;           // row within the wave's 4-row group
    const int slot = lane & 15;            // linear LDS f4 slot within the row

    auto issue = [&](int s, int buf) {
        const int n0 = (nt0 + s) * 64;
        float4* base0 = t + buf * 1024;
#pragma unroll
        for (int p = 0; p < 4; ++p) {
            int row = p * 16 + wave * 4 + lrow4;
            int csrc = slot ^ ((row >> 2) & 15);   // pre-swizzled source column
            async_ld16((const bf16_t*)(src + (size_t)(k0 + row) * N + n0 + csrc * 4),
                       (bf16_t*)(base0 + (p * 16 + wave * 4) * 16));
        }
    };

    auto phase2 = [&](int s, int buf) {
        const int n0 = (nt0 + s) * 64;
        const float* tf = (const float*)(t + buf * 1024);
        const int n = tid >> 2, b = tid & 3;
        float v[16];
#pragma unroll
        for (int i = 0; i < 16; ++i) {
            int k = 16 * b + i;
            int f4 = k * 16 + ((n >> 2) ^ ((k >> 2) & 15));
            v[i] = tf[f4 * 4 + (n & 3)];
        }
        bf16x8 h0, h1;
#pragma unroll
        for (int i = 0; i < 8; ++i) { h0[i] = (bf16_t)v[i]; h1[i] = (bf16_t)v[8 + i]; }
        size_t oi = (size_t)(n0 + n) * K + k0 + 16 * b;
        *(bf16x8*)(outh + oi) = h0;
        *(bf16x8*)(outh + oi + 8) = h1;
        if constexpr (LO) {
            bf16x8 l0, l1;
#pragma unroll
            for (int i = 0; i < 8; ++i) {
                l0[i] = (bf16_t)(v[i] - (float)h0[i]);
                l1[i] = (bf16_t)(v[8 + i] - (float)h1[i]);
            }
            *(bf16x8*)(outl + oi) = l0;
            *(bf16x8*)(outl + oi + 8) = l1;
        }
    };

    issue(0, 0);
#pragma unroll
    for (int s = 0; s < 4; ++s) {
        if (s < 3) {
            issue(s + 1, (s + 1) & 1);
            asm volatile("s_waitcnt vmcnt(4)" ::: "memory");   // tile s landed; s+1 in flight
        } else {
            asm volatile("s_waitcnt vmcnt(0)" ::: "memory");
        }
        __builtin_amdgcn_s_barrier();
        __builtin_amdgcn_sched_barrier(0);   // rule 18: no hoist across raw barrier
        phase2(s, s & 1);
        __builtin_amdgcn_sched_barrier(0);   // pin phase-2 reads before reuse barrier
        if (s < 3) __builtin_amdgcn_s_barrier();
        __builtin_amdgcn_sched_barrier(0);
    }
}

#define NCVT2 2048                       // BATCH*DM/8/256
#define NSLAB_SQ 64                      // per square mat: 16 kt x 4 slabs
#define NSLAB_W1 1024                    // 8 mats * (16 kt x 8 slabs)
#define NSLAB_W2 1024                    // 8 mats * (32 kt x 4 slabs)
#define PREP_GRID (NCVT2 + NSLAB_SQ + NSLAB_SQ + NSLAB_W1 + NSLAB_W2)

__global__ __launch_bounds__(256) void prep_kernel(
    const float* __restrict__ x, const float* __restrict__ Wr1, const float* __restrict__ Wo,
    const float* __restrict__ W1, const float* __restrict__ W2,
    bf16_t* __restrict__ xh, bf16_t* __restrict__ xl,
    bf16_t* __restrict__ Wr1h, bf16_t* __restrict__ Wr1l, bf16_t* __restrict__ Wot,
    bf16_t* __restrict__ W1t, bf16_t* __restrict__ W2t) {
    __shared__ float4 t[2 * 64 * 16];    // 32KB (double-buffered slab)
    int b = blockIdx.x;
    if (b < NCVT2) {                     // x -> hi/lo bf16 split, 32B/lane
        size_t i = (size_t)b * 256 + threadIdx.x;
        const float4* x4 = (const float4*)x;
        float4 v0 = x4[2 * i], v1 = x4[2 * i + 1];
        float f[8] = {v0.x, v0.y, v0.z, v0.w, v1.x, v1.y, v1.z, v1.w};
        bf16x8 h, l;
#pragma unroll
        for (int j = 0; j < 8; ++j) { h[j] = (bf16_t)f[j]; l[j] = (bf16_t)(f[j] - (float)h[j]); }
        *(bf16x8*)(xh + i * 8) = h;
        *(bf16x8*)(xl + i * 8) = l;
        return;
    }
    b -= NCVT2;
    if (b < NSLAB_SQ) { tslab_body<true >(Wr1, Wr1h, Wr1l, DM, DM, b >> 2, (b & 3) * 4, t); return; }
    b -= NSLAB_SQ;
    if (b < NSLAB_SQ) { tslab_body<false>(Wo, Wot, nullptr, DM, DM, b >> 2, (b & 3) * 4, t); return; }
    b -= NSLAB_SQ;
    if (b < NSLAB_W1) {                  // W1: (1024k, 2048n) -> 16 kt x 8 slabs
        int mat = b >> 7, r = b & 127;
        size_t off = (size_t)mat * DM * DFF;
        tslab_body<false>(W1 + off, W1t + off, nullptr, DM, DFF, r >> 3, (r & 7) * 4, t);
        return;
    }
    b -= NSLAB_W1;
    {                                    // W2: (2048k, 1024n) -> 32 kt x 4 slabs
        int mat = b >> 7, r = b & 127;
        size_t off = (size_t)mat * DM * DFF;
        tslab_body<false>(W2 + off, W2t + off, nullptr, DFF, DM, r >> 2, (r & 3) * 4, t);
    }
}

// ---------------- GEMM: C[M,N] = A[M,K] @ Bt[N,K]^T (+bias, opt gelu) ----------------
// REVERTED to the round-1 structure (known-good 365us): 128x128 tile, BK=32,
// 8 waves (2x4: wave tile 64x32), global_load_lds width-16, 2-stage LDS
// double-buffer with one __syncthreads per K-step. Round-2's counted-vmcnt /
// sched_barrier / setprio grafts regressed (m131-m141 pattern) and are removed.
template<bool SPLIT, bool GATHER, bool GELU, bool SCATTER, bool OUTF32>
__global__ __launch_bounds__(512) void gemm_kernel(
    const bf16_t* __restrict__ A, const bf16_t* __restrict__ Alo,
    const bf16_t* __restrict__ Bt, const bf16_t* __restrict__ Btlo,
    const float* __restrict__ bias,
    float* __restrict__ outF, bf16_t* __restrict__ outB,
    const int* __restrict__ perm, const int* __restrict__ counts,
    int M, int N, int K) {
    int tile = 0, rb, cnt = M;
    const int* permT = nullptr;
    if constexpr (GATHER) {
        int xb = blockIdx.x, t = 0, c = 0;
        while (t < NTILES) {
            c = counts[t];
            int nbk = (c + 127) >> 7;
            if (xb < nbk) break;
            xb -= nbk; ++t;
        }
        if (t == NTILES) return;          // beyond total routed blocks (uniform)
        tile = t;
        rb = xb * 128;
        cnt = c;
        permT = perm + tile * BATCH;
    } else {
        rb = blockIdx.x * 128;
    }
    Bt   += (size_t)tile * K * N;
    if constexpr (SPLIT) Btlo += (size_t)tile * K * N;
    bias += (size_t)tile * N;

    constexpr int BUF = 128 * 32;          // elements per buffer (8KB)
    __shared__ __align__(16) bf16_t As[2 * BUF];
    __shared__ __align__(16) bf16_t Bs[2 * BUF];
    __shared__ __align__(16) bf16_t Asl[SPLIT ? 2 * BUF : 8];
    __shared__ __align__(16) bf16_t Bsl[SPLIT ? 2 * BUF : 8];

    const int lane = threadIdx.x & 63;
    const int wave = threadIdx.x >> 6;     // 0..7
    const int wm = wave & 1, wn = wave >> 1;   // 2 x 4 wave grid
    const int nb = blockIdx.y * 128;

    // staging source offsets (one 16B lane-load per matrix per K-step)
    const int srow = lane >> 2;                       // 0..15 within wave's 16-row seg
    const int scol = ((lane & 3) ^ (srow & 3)) * 8;   // swizzled k-chunk (elements)
    const int row = wave * 16 + srow;                 // 0..127
    int arow;
    if constexpr (GATHER) {
        int pos = rb + row;
        if (pos > cnt - 1) pos = cnt - 1;
        arow = permT[pos];
    } else {
        arow = rb + row;
    }
    const size_t aoff = (size_t)arow * K + scol;
    const size_t boff = (size_t)(nb + row) * K + scol;

    f32x4 acc[4][2];
#pragma unroll
    for (int i = 0; i < 4; ++i)
#pragma unroll
        for (int j = 0; j < 2; ++j) acc[i][j] = (f32x4){0.f, 0.f, 0.f, 0.f};

    const int lr = lane & 15, lq = lane >> 4;
    const int rdoff = (lr * 4 + (lq ^ (lr & 3))) * 8;

    auto stage = [&](int k0, int buf) {
        async_ld16(A  + aoff + k0, &As[buf * BUF + wave * 512]);
        async_ld16(Bt + boff + k0, &Bs[buf * BUF + wave * 512]);
        if constexpr (SPLIT) {
            async_ld16(Alo  + aoff + k0, &Asl[buf * BUF + wave * 512]);
            async_ld16(Btlo + boff + k0, &Bsl[buf * BUF + wave * 512]);
        }
    };

    auto compute = [&](int cur) {
        bf16x8 af[4], bfr[2], afl[4], bfl[2];
#pragma unroll
        for (int i = 0; i < 4; ++i) {
            af[i] = *(const bf16x8*)&As[cur * BUF + (wm * 4 + i) * 512 + rdoff];
            if constexpr (SPLIT)
                afl[i] = *(const bf16x8*)&Asl[cur * BUF + (wm * 4 + i) * 512 + rdoff];
        }
#pragma unroll
        for (int j = 0; j < 2; ++j) {
            bfr[j] = *(const bf16x8*)&Bs[cur * BUF + (wn * 2 + j) * 512 + rdoff];
            if constexpr (SPLIT)
                bfl[j] = *(const bf16x8*)&Bsl[cur * BUF + (wn * 2 + j) * 512 + rdoff];
        }
#pragma unroll
        for (int i = 0; i < 4; ++i)
#pragma unroll
            for (int j = 0; j < 2; ++j) {
                acc[i][j] = mfma16(af[i], bfr[j], acc[i][j]);
                if constexpr (SPLIT) {
                    // hi*lo cross terms; lo*lo ~1e-6, dropped
                    acc[i][j] = mfma16(af[i], bfl[j], acc[i][j]);
                    acc[i][j] = mfma16(afl[i], bfr[j], acc[i][j]);
                }
            }
    };

    stage(0, 0);
    int cur = 0;
    for (int k0 = 0; k0 < K; k0 += 32, cur ^= 1) {
        __syncthreads();                  // drains vmcnt: buf[cur] ready
        if (k0 + 32 < K) stage(k0 + 32, cur ^ 1);
        compute(cur);
    }

    // epilogue: C row = (lane>>4)*4 + reg, col = lane&15 (m89/m91-verified)
#pragma unroll
    for (int i = 0; i < 4; ++i) {
#pragma unroll
        for (int j = 0; j < 2; ++j) {
#pragma unroll
            for (int r = 0; r < 4; ++r) {
                int m = wm * 64 + i * 16 + lq * 4 + r;
                int n = wn * 32 + j * 16 + lr;
                int pos = rb + m;
                if constexpr (GATHER) { if (pos >= cnt) continue; }
                int grow;
                if constexpr (SCATTER) grow = permT[pos];
                else                   grow = pos;
                int gn = nb + n;
                float v = acc[i][j][r] + bias[gn];
                if constexpr (GELU) v = gelu_exact(v);
                if constexpr (OUTF32) outF[(size_t)grow * N + gn] = v;
                else                  outB[(size_t)grow * N + gn] = (bf16_t)v;
            }
        }
    }
}

// ---------------- router layer2 + argmax + routing lists ----------------
// (unchanged)
__global__ __launch_bounds__(256) void router2_kernel(
    const float* __restrict__ Hr, const float* __restrict__ Wr2, const float* __restrict__ br2,
    float* __restrict__ outLog, float* __restrict__ outIdx,
    int* __restrict__ counts, int* __restrict__ perm) {
    __shared__ float w2s[DM * 9];
    __shared__ int h[NTILES], base[NTILES];
    const int tid = threadIdx.x;
    if (tid < NTILES) h[tid] = 0;
    for (int e = tid; e < DM * 8; e += 256) {
        int k = e >> 3, j = e & 7;
        w2s[k * 9 + j] = Wr2[e];
    }
    __syncthreads();

    const int lane = tid & 63, wave = tid >> 6;
    const int sub = lane >> 4;
    const int lr16 = lane & 15;
    const int row = blockIdx.x * 16 + wave * 4 + sub;

    const float4* Hr4 = (const float4*)Hr;
    float acc[8];
#pragma unroll
    for (int j = 0; j < 8; ++j) acc[j] = 0.f;

#pragma unroll
    for (int i = 0; i < 16; ++i) {
        int f = lr16 + i * 16;
        float4 hv = Hr4[(size_t)row * 256 + f];
        float hx[4] = {hv.x, hv.y, hv.z, hv.w};
        int kbase = f * 4;
#pragma unroll
        for (int d = 0; d < 4; ++d) {
            float xv = hx[d];
            const float* w = &w2s[(kbase + d) * 9];
#pragma unroll
            for (int j = 0; j < 8; ++j) acc[j] += xv * w[j];
        }
    }
#pragma unroll
    for (int off = 8; off; off >>= 1)
#pragma unroll
        for (int j = 0; j < 8; ++j) acc[j] += __shfl_down(acc[j], off);

    int bi = 0, rank = 0;
    if (lr16 == 0) {
        float best = -1e30f;
        float lg[8];
#pragma unroll
        for (int j = 0; j < 8; ++j) {
            float v = (acc[j] + br2[j]) * 2.0f;   // /TEMPERATURE, T=0.5
            lg[j] = v;
            if (v > best) { best = v; bi = j; }   // strict > == first-max (jnp.argmax)
        }
        float4 lo = {lg[0], lg[1], lg[2], lg[3]};
        float4 hi = {lg[4], lg[5], lg[6], lg[7]};
        *(float4*)(outLog + (size_t)row * 8)     = lo;
        *(float4*)(outLog + (size_t)row * 8 + 4) = hi;
        outIdx[row] = (float)bi;
        rank = atomicAdd(&h[bi], 1);
    }
    __syncthreads();
    if (tid < NTILES && h[tid] > 0) base[tid] = atomicAdd(&counts[tid], h[tid]);
    __syncthreads();
    if (lr16 == 0) perm[bi * BATCH + base[bi] + rank] = row;
}

// ---------------- host launch ----------------
extern "C" void kernel_launch(void* const* d_in, const int* in_sizes, int n_in,
                              void* d_out, int out_size, void* d_ws, size_t ws_size,
                              hipStream_t stream) {
    const float* x   = (const float*)d_in[0];
    const float* Wr1 = (const float*)d_in[1];
    const float* br1 = (const float*)d_in[2];
    const float* Wr2 = (const float*)d_in[3];
    const float* br2 = (const float*)d_in[4];
    const float* W1  = (const float*)d_in[5];
    const float* b1  = (const float*)d_in[6];
    const float* W2  = (const float*)d_in[7];
    const float* b2  = (const float*)d_in[8];
    const float* Wo  = (const float*)d_in[9];
    const float* bo  = (const float*)d_in[10];

    char* ws = (char*)d_ws;
    size_t o = 0;
    auto carve = [&](size_t bytes) { char* p = ws + o; o = (o + bytes + 255) & ~(size_t)255; return p; };
    bf16_t* Wr1h = (bf16_t*)carve((size_t)DM * DM * 2);
    bf16_t* Wr1l = (bf16_t*)carve((size_t)DM * DM * 2);
    bf16_t* Wot  = (bf16_t*)carve((size_t)DM * DM * 2);
    bf16_t* W1t  = (bf16_t*)carve((size_t)NTILES * DM * DFF * 2);
    bf16_t* W2t  = (bf16_t*)carve((size_t)NTILES * DM * DFF * 2);
    bf16_t* xh   = (bf16_t*)carve((size_t)BATCH * DM * 2);
    bf16_t* xl   = (bf16_t*)carve((size_t)BATCH * DM * 2);
    bf16_t* H1   = (bf16_t*)carve((size_t)BATCH * DFF * 2);
    bf16_t* sel  = (bf16_t*)carve((size_t)BATCH * DM * 2);
    float*  Hr   = (float*)carve((size_t)BATCH * DM * 4);
    int*    counts = (int*)carve(NTILES * sizeof(int));
    int*    perm   = (int*)carve((size_t)NTILES * BATCH * sizeof(int));

    float* outMain = (float*)d_out;
    float* outIdx  = outMain + (size_t)BATCH * DM;
    float* outLog  = outIdx + BATCH;

    hipMemsetAsync(counts, 0, NTILES * sizeof(int), stream);

    prep_kernel<<<PREP_GRID, 256, 0, stream>>>(x, Wr1, Wo, W1, W2,
                                               xh, xl, Wr1h, Wr1l, Wot, W1t, W2t);

    // router layer 1: Hr = gelu(x @ Wr1 + br1), hi/lo split for fp32-class accuracy
    gemm_kernel<true, false, true, false, true><<<dim3(BATCH / 128, DM / 128, 1), 512, 0, stream>>>(
        xh, xl, Wr1h, Wr1l, br1, Hr, nullptr, nullptr, nullptr, BATCH, DM, DM);

    router2_kernel<<<BATCH / 16, 256, 0, stream>>>(Hr, Wr2, br2, outLog, outIdx, counts, perm);

    // expert layer 1: H1[token] = gelu(x[token] @ W1[t] + b1[t]), gathered+scattered
    gemm_kernel<false, true, true, true, false><<<dim3(MAXXB, DFF / 128, 1), 512, 0, stream>>>(
        xh, nullptr, W1t, nullptr, b1, nullptr, H1, perm, counts, BATCH, DFF, DM);

    // expert layer 2: sel[token] = H1[token] @ W2[t] + b2[t]
    gemm_kernel<false, true, false, true, false><<<dim3(MAXXB, DM / 128, 1), 512, 0, stream>>>(
        H1, nullptr, W2t, nullptr, b2, nullptr, sel, perm, counts, BATCH, DM, DFF);

    // output projection: out = sel @ Wo + bo
    gemm_kernel<false, false, false, false, true><<<dim3(BATCH / 128, DM / 128, 1), 512, 0, stream>>>(
        sel, nullptr, Wot, nullptr, bo, outMain, nullptr, nullptr, nullptr, BATCH, DM, DM);
}

// Round 4
// 367.410 us; speedup vs baseline: 1.0865x; 1.0098x over previous
//
#include <hip/hip_runtime.h>
#include <hip/hip_bf16.h>
#include <math.h>
#include <stdint.h>

typedef __bf16 bf16_t;
typedef __bf16 bf16x4 __attribute__((ext_vector_type(4)));
typedef __bf16 bf16x8 __attribute__((ext_vector_type(8)));
typedef float  f32x4  __attribute__((ext_vector_type(4)));

#define BATCH   4096
#define DM      1024
#define DFF     2048
#define NTILES  8
#define MAXXB   40   // max compacted x-blocks: 32 + 7 partials

__device__ __forceinline__ float gelu_exact(float x) {
    return 0.5f * x * (1.0f + erff(x * 0.70710678118654752440f));
}

__device__ __forceinline__ void async_ld16(const bf16_t* g, bf16_t* l) {
    __builtin_amdgcn_global_load_lds(
        (const __attribute__((address_space(1))) void*)g,
        (__attribute__((address_space(3))) void*)l, 16, 0, 0);
}

__device__ __forceinline__ f32x4 mfma16(bf16x8 a, bf16x8 b, f32x4 c) {
    return __builtin_amdgcn_mfma_f32_16x16x32_bf16(a, b, c, 0, 0, 0);
}

// ---------------- fused prep: x hi/lo split + 4 weight transposes ----------------
// REVERTED to round-1 (proven 73us): 64x64 tile per block, 16KB LDS, high
// block-level TLP. Round-3's 64x256 slab pipeline halved occupancy (33%) and
// regressed — inter-block overlap was doing the latency hiding.
template<bool LO>
__device__ void tconv64_body(const float* __restrict__ src, bf16_t* __restrict__ outh,
                             bf16_t* __restrict__ outl, int K, int N, int kt, int nt,
                             float4* t /* 64*16 float4 = 16KB */) {
    const int tid = threadIdx.x;
    const int k0 = kt * 64, n0 = nt * 64;
#pragma unroll
    for (int p = 0; p < 4; ++p) {
        int row = p * 16 + (tid >> 4);
        int c = tid & 15;
        float4 v = *(const float4*)(src + (size_t)(k0 + row) * N + n0 + c * 4);
        t[row * 16 + (c ^ ((row >> 2) & 15))] = v;
    }
    __syncthreads();
    const int n = tid >> 2, b = tid & 3;
    const float* tf = (const float*)t;
    float v[16];
#pragma unroll
    for (int i = 0; i < 16; ++i) {
        int k = 16 * b + i;
        int f4 = k * 16 + ((n >> 2) ^ ((k >> 2) & 15));
        v[i] = tf[f4 * 4 + (n & 3)];
    }
    bf16x8 h0, h1;
#pragma unroll
    for (int i = 0; i < 8; ++i) { h0[i] = (bf16_t)v[i]; h1[i] = (bf16_t)v[8 + i]; }
    size_t oi = (size_t)(n0 + n) * K + k0 + 16 * b;
    *(bf16x8*)(outh + oi) = h0;
    *(bf16x8*)(outh + oi + 8) = h1;
    if constexpr (LO) {
        bf16x8 l0, l1;
#pragma unroll
        for (int i = 0; i < 8; ++i) {
            l0[i] = (bf16_t)(v[i] - (float)h0[i]);
            l1[i] = (bf16_t)(v[8 + i] - (float)h1[i]);
        }
        *(bf16x8*)(outl + oi) = l0;
        *(bf16x8*)(outl + oi + 8) = l1;
    }
}

#define NCVT2 2048
#define NSQ64 256
#define NW1   4096
#define NW2   4096
#define PREP_GRID (NCVT2 + NSQ64 + NSQ64 + NW1 + NW2)

__global__ __launch_bounds__(256) void prep_kernel(
    const float* __restrict__ x, const float* __restrict__ Wr1, const float* __restrict__ Wo,
    const float* __restrict__ W1, const float* __restrict__ W2,
    bf16_t* __restrict__ xh, bf16_t* __restrict__ xl,
    bf16_t* __restrict__ Wr1h, bf16_t* __restrict__ Wr1l, bf16_t* __restrict__ Wot,
    bf16_t* __restrict__ W1t, bf16_t* __restrict__ W2t) {
    __shared__ float4 t[64 * 16];
    int b = blockIdx.x;
    if (b < NCVT2) {
        size_t i = (size_t)b * 256 + threadIdx.x;
        const float4* x4 = (const float4*)x;
        float4 v0 = x4[2 * i], v1 = x4[2 * i + 1];
        float f[8] = {v0.x, v0.y, v0.z, v0.w, v1.x, v1.y, v1.z, v1.w};
        bf16x8 h, l;
#pragma unroll
        for (int j = 0; j < 8; ++j) { h[j] = (bf16_t)f[j]; l[j] = (bf16_t)(f[j] - (float)h[j]); }
        *(bf16x8*)(xh + i * 8) = h;
        *(bf16x8*)(xl + i * 8) = l;
        return;
    }
    b -= NCVT2;
    if (b < NSQ64) { tconv64_body<true >(Wr1, Wr1h, Wr1l, DM, DM, b >> 4, b & 15, t); return; }
    b -= NSQ64;
    if (b < NSQ64) { tconv64_body<false>(Wo, Wot, nullptr, DM, DM, b >> 4, b & 15, t); return; }
    b -= NSQ64;
    if (b < NW1) {
        int mat = b >> 9, r = b & 511;
        size_t off = (size_t)mat * DM * DFF;
        tconv64_body<false>(W1 + off, W1t + off, nullptr, DM, DFF, r >> 5, r & 31, t);
        return;
    }
    b -= NW1;
    {
        int mat = b >> 9, r = b & 511;
        size_t off = (size_t)mat * DM * DFF;
        tconv64_body<false>(W2 + off, W2t + off, nullptr, DFF, DM, r >> 4, r & 15, t);
    }
}

// ---------------- GEMM: C[M,N] = A[M,K] @ Bt[N,K]^T (+bias, opt gelu) ----------------
// Round-1 structure with BK=64 (two 32-k chunks per buffer stage). Halves the
// per-K barrier/drain count (the 1-block/CU shapes' main stall) and doubles
// prefetch flight time; ds_read/MFMA/staging instruction totals unchanged.
// LDS: non-split 64KB (2 blocks/CU still possible for the gathered grids),
// SPLIT 128KB (router1 is grid-bound at 1 block/CU anyway).
// Staging map per 32-chunk (XOR swizzle) identical to round-1.
template<bool SPLIT, bool GATHER, bool GELU, bool SCATTER, bool OUTF32>
__global__ __launch_bounds__(512) void gemm_kernel(
    const bf16_t* __restrict__ A, const bf16_t* __restrict__ Alo,
    const bf16_t* __restrict__ Bt, const bf16_t* __restrict__ Btlo,
    const float* __restrict__ bias,
    float* __restrict__ outF, bf16_t* __restrict__ outB,
    const int* __restrict__ perm, const int* __restrict__ counts,
    int M, int N, int K) {
    int tile = 0, rb, cnt = M;
    const int* permT = nullptr;
    if constexpr (GATHER) {
        int xb = blockIdx.x, t = 0, c = 0;
        while (t < NTILES) {
            c = counts[t];
            int nbk = (c + 127) >> 7;
            if (xb < nbk) break;
            xb -= nbk; ++t;
        }
        if (t == NTILES) return;          // beyond total routed blocks (uniform)
        tile = t;
        rb = xb * 128;
        cnt = c;
        permT = perm + tile * BATCH;
    } else {
        rb = blockIdx.x * 128;
    }
    Bt   += (size_t)tile * K * N;
    if constexpr (SPLIT) Btlo += (size_t)tile * K * N;
    bias += (size_t)tile * N;

    constexpr int CH  = 128 * 32;          // elements per 32-k chunk (8KB)
    constexpr int BUF = 2 * CH;            // elements per K-step buffer (16KB)
    __shared__ __align__(16) bf16_t As[2 * BUF];
    __shared__ __align__(16) bf16_t Bs[2 * BUF];
    __shared__ __align__(16) bf16_t Asl[SPLIT ? 2 * BUF : 8];
    __shared__ __align__(16) bf16_t Bsl[SPLIT ? 2 * BUF : 8];

    const int lane = threadIdx.x & 63;
    const int wave = threadIdx.x >> 6;     // 0..7
    const int wm = wave & 1, wn = wave >> 1;   // 2 x 4 wave grid
    const int nb = blockIdx.y * 128;

    // staging source offsets (one 16B lane-load per matrix per 32-chunk)
    const int srow = lane >> 2;                       // 0..15 within wave's 16-row seg
    const int scol = ((lane & 3) ^ (srow & 3)) * 8;   // swizzled k-chunk (elements)
    const int row = wave * 16 + srow;                 // 0..127
    int arow;
    if constexpr (GATHER) {
        int pos = rb + row;
        if (pos > cnt - 1) pos = cnt - 1;
        arow = permT[pos];
    } else {
        arow = rb + row;
    }
    const size_t aoff = (size_t)arow * K + scol;
    const size_t boff = (size_t)(nb + row) * K + scol;

    f32x4 acc[4][2];
#pragma unroll
    for (int i = 0; i < 4; ++i)
#pragma unroll
        for (int j = 0; j < 2; ++j) acc[i][j] = (f32x4){0.f, 0.f, 0.f, 0.f};

    const int lr = lane & 15, lq = lane >> 4;
    const int rdoff = (lr * 4 + (lq ^ (lr & 3))) * 8;

    auto stage = [&](int k0, int buf) {
#pragma unroll
        for (int c = 0; c < 2; ++c) {
            async_ld16(A  + aoff + k0 + c * 32, &As[buf * BUF + c * CH + wave * 512]);
            async_ld16(Bt + boff + k0 + c * 32, &Bs[buf * BUF + c * CH + wave * 512]);
            if constexpr (SPLIT) {
                async_ld16(Alo  + aoff + k0 + c * 32, &Asl[buf * BUF + c * CH + wave * 512]);
                async_ld16(Btlo + boff + k0 + c * 32, &Bsl[buf * BUF + c * CH + wave * 512]);
            }
        }
    };

    auto compute = [&](int cur) {
#pragma unroll
        for (int kk = 0; kk < 2; ++kk) {
            const int base = cur * BUF + kk * CH;
            bf16x8 af[4], bfr[2], afl[4], bfl[2];
#pragma unroll
            for (int i = 0; i < 4; ++i) {
                af[i] = *(const bf16x8*)&As[base + (wm * 4 + i) * 512 + rdoff];
                if constexpr (SPLIT)
                    afl[i] = *(const bf16x8*)&Asl[base + (wm * 4 + i) * 512 + rdoff];
            }
#pragma unroll
            for (int j = 0; j < 2; ++j) {
                bfr[j] = *(const bf16x8*)&Bs[base + (wn * 2 + j) * 512 + rdoff];
                if constexpr (SPLIT)
                    bfl[j] = *(const bf16x8*)&Bsl[base + (wn * 2 + j) * 512 + rdoff];
            }
#pragma unroll
            for (int i = 0; i < 4; ++i)
#pragma unroll
                for (int j = 0; j < 2; ++j) {
                    acc[i][j] = mfma16(af[i], bfr[j], acc[i][j]);
                    if constexpr (SPLIT) {
                        // hi*lo cross terms; lo*lo ~1e-6, dropped
                        acc[i][j] = mfma16(af[i], bfl[j], acc[i][j]);
                        acc[i][j] = mfma16(afl[i], bfr[j], acc[i][j]);
                    }
                }
        }
    };

    stage(0, 0);
    int cur = 0;
    for (int k0 = 0; k0 < K; k0 += 64, cur ^= 1) {
        __syncthreads();                  // drains vmcnt: buf[cur] ready
        if (k0 + 64 < K) stage(k0 + 64, cur ^ 1);
        compute(cur);
    }

    // epilogue: C row = (lane>>4)*4 + reg, col = lane&15 (m89/m91-verified)
#pragma unroll
    for (int i = 0; i < 4; ++i) {
#pragma unroll
        for (int j = 0; j < 2; ++j) {
#pragma unroll
            for (int r = 0; r < 4; ++r) {
                int m = wm * 64 + i * 16 + lq * 4 + r;
                int n = wn * 32 + j * 16 + lr;
                int pos = rb + m;
                if constexpr (GATHER) { if (pos >= cnt) continue; }
                int grow;
                if constexpr (SCATTER) grow = permT[pos];
                else                   grow = pos;
                int gn = nb + n;
                float v = acc[i][j][r] + bias[gn];
                if constexpr (GELU) v = gelu_exact(v);
                if constexpr (OUTF32) outF[(size_t)grow * N + gn] = v;
                else                  outB[(size_t)grow * N + gn] = (bf16_t)v;
            }
        }
    }
}

// ---------------- router layer2 + argmax + routing lists ----------------
// (unchanged)
__global__ __launch_bounds__(256) void router2_kernel(
    const float* __restrict__ Hr, const float* __restrict__ Wr2, const float* __restrict__ br2,
    float* __restrict__ outLog, float* __restrict__ outIdx,
    int* __restrict__ counts, int* __restrict__ perm) {
    __shared__ float w2s[DM * 9];
    __shared__ int h[NTILES], base[NTILES];
    const int tid = threadIdx.x;
    if (tid < NTILES) h[tid] = 0;
    for (int e = tid; e < DM * 8; e += 256) {
        int k = e >> 3, j = e & 7;
        w2s[k * 9 + j] = Wr2[e];
    }
    __syncthreads();

    const int lane = tid & 63, wave = tid >> 6;
    const int sub = lane >> 4;
    const int lr16 = lane & 15;
    const int row = blockIdx.x * 16 + wave * 4 + sub;

    const float4* Hr4 = (const float4*)Hr;
    float acc[8];
#pragma unroll
    for (int j = 0; j < 8; ++j) acc[j] = 0.f;

#pragma unroll
    for (int i = 0; i < 16; ++i) {
        int f = lr16 + i * 16;
        float4 hv = Hr4[(size_t)row * 256 + f];
        float hx[4] = {hv.x, hv.y, hv.z, hv.w};
        int kbase = f * 4;
#pragma unroll
        for (int d = 0; d < 4; ++d) {
            float xv = hx[d];
            const float* w = &w2s[(kbase + d) * 9];
#pragma unroll
            for (int j = 0; j < 8; ++j) acc[j] += xv * w[j];
        }
    }
#pragma unroll
    for (int off = 8; off; off >>= 1)
#pragma unroll
        for (int j = 0; j < 8; ++j) acc[j] += __shfl_down(acc[j], off);

    int bi = 0, rank = 0;
    if (lr16 == 0) {
        float best = -1e30f;
        float lg[8];
#pragma unroll
        for (int j = 0; j < 8; ++j) {
            float v = (acc[j] + br2[j]) * 2.0f;   // /TEMPERATURE, T=0.5
            lg[j] = v;
            if (v > best) { best = v; bi = j; }   // strict > == first-max (jnp.argmax)
        }
        float4 lo = {lg[0], lg[1], lg[2], lg[3]};
        float4 hi = {lg[4], lg[5], lg[6], lg[7]};
        *(float4*)(outLog + (size_t)row * 8)     = lo;
        *(float4*)(outLog + (size_t)row * 8 + 4) = hi;
        outIdx[row] = (float)bi;
        rank = atomicAdd(&h[bi], 1);
    }
    __syncthreads();
    if (tid < NTILES && h[tid] > 0) base[tid] = atomicAdd(&counts[tid], h[tid]);
    __syncthreads();
    if (lr16 == 0) perm[bi * BATCH + base[bi] + rank] = row;
}

// ---------------- host launch ----------------
extern "C" void kernel_launch(void* const* d_in, const int* in_sizes, int n_in,
                              void* d_out, int out_size, void* d_ws, size_t ws_size,
                              hipStream_t stream) {
    const float* x   = (const float*)d_in[0];
    const float* Wr1 = (const float*)d_in[1];
    const float* br1 = (const float*)d_in[2];
    const float* Wr2 = (const float*)d_in[3];
    const float* br2 = (const float*)d_in[4];
    const float* W1  = (const float*)d_in[5];
    const float* b1  = (const float*)d_in[6];
    const float* W2  = (const float*)d_in[7];
    const float* b2  = (const float*)d_in[8];
    const float* Wo  = (const float*)d_in[9];
    const float* bo  = (const float*)d_in[10];

    char* ws = (char*)d_ws;
    size_t o = 0;
    auto carve = [&](size_t bytes) { char* p = ws + o; o = (o + bytes + 255) & ~(size_t)255; return p; };
    bf16_t* Wr1h = (bf16_t*)carve((size_t)DM * DM * 2);
    bf16_t* Wr1l = (bf16_t*)carve((size_t)DM * DM * 2);
    bf16_t* Wot  = (bf16_t*)carve((size_t)DM * DM * 2);
    bf16_t* W1t  = (bf16_t*)carve((size_t)NTILES * DM * DFF * 2);
    bf16_t* W2t  = (bf16_t*)carve((size_t)NTILES * DM * DFF * 2);
    bf16_t* xh   = (bf16_t*)carve((size_t)BATCH * DM * 2);
    bf16_t* xl   = (bf16_t*)carve((size_t)BATCH * DM * 2);
    bf16_t* H1   = (bf16_t*)carve((size_t)BATCH * DFF * 2);
    bf16_t* sel  = (bf16_t*)carve((size_t)BATCH * DM * 2);
    float*  Hr   = (float*)carve((size_t)BATCH * DM * 4);
    int*    counts = (int*)carve(NTILES * sizeof(int));
    int*    perm   = (int*)carve((size_t)NTILES * BATCH * sizeof(int));

    float* outMain = (float*)d_out;
    float* outIdx  = outMain + (size_t)BATCH * DM;
    float* outLog  = outIdx + BATCH;

    hipMemsetAsync(counts, 0, NTILES * sizeof(int), stream);

    prep_kernel<<<PREP_GRID, 256, 0, stream>>>(x, Wr1, Wo, W1, W2,
                                               xh, xl, Wr1h, Wr1l, Wot, W1t, W2t);

    // router layer 1: Hr = gelu(x @ Wr1 + br1), hi/lo split for fp32-class accuracy
    gemm_kernel<true, false, true, false, true><<<dim3(BATCH / 128, DM / 128, 1), 512, 0, stream>>>(
        xh, xl, Wr1h, Wr1l, br1, Hr, nullptr, nullptr, nullptr, BATCH, DM, DM);

    router2_kernel<<<BATCH / 16, 256, 0, stream>>>(Hr, Wr2, br2, outLog, outIdx, counts, perm);

    // expert layer 1: H1[token] = gelu(x[token] @ W1[t] + b1[t]), gathered+scattered
    gemm_kernel<false, true, true, true, false><<<dim3(MAXXB, DFF / 128, 1), 512, 0, stream>>>(
        xh, nullptr, W1t, nullptr, b1, nullptr, H1, perm, counts, BATCH, DFF, DM);

    // expert layer 2: sel[token] = H1[token] @ W2[t] + b2[t]
    gemm_kernel<false, true, false, true, false><<<dim3(MAXXB, DM / 128, 1), 512, 0, stream>>>(
        H1, nullptr, W2t, nullptr, b2, nullptr, sel, perm, counts, BATCH, DM, DFF);

    // output projection: out = sel @ Wo + bo
    gemm_kernel<false, false, false, false, true><<<dim3(BATCH / 128, DM / 128, 1), 512, 0, stream>>>(
        sel, nullptr, Wot, nullptr, bo, outMain, nullptr, nullptr, nullptr, BATCH, DM, DM);
}

// Round 6
// 340.105 us; speedup vs baseline: 1.1737x; 1.0803x over previous
//
#include <hip/hip_runtime.h>
#include <hip/hip_bf16.h>
#include <math.h>
#include <stdint.h>

typedef __bf16 bf16_t;
typedef __bf16 bf16x8 __attribute__((ext_vector_type(8)));
typedef float  f32x4  __attribute__((ext_vector_type(4)));

#define BATCH   4096
#define DM      1024
#define DFF     2048
#define NTILES  8
#define MAXXB   40   // max compacted x-blocks: 32 + 7 partials

__device__ __forceinline__ float gelu_exact(float x) {
    return 0.5f * x * (1.0f + erff(x * 0.70710678118654752440f));
}

__device__ __forceinline__ void async_ld16(const bf16_t* g, bf16_t* l) {
    __builtin_amdgcn_global_load_lds(
        (const __attribute__((address_space(1))) void*)g,
        (__attribute__((address_space(3))) void*)l, 16, 0, 0);
}

__device__ __forceinline__ f32x4 mfma16(bf16x8 a, bf16x8 b, f32x4 c) {
    return __builtin_amdgcn_mfma_f32_16x16x32_bf16(a, b, c, 0, 0, 0);
}

// ---------------- 64x64 transpose+convert tile (round-1-proven math) ----------------
// Parameterized by tid so it can run as a 256-thread half of a 512-thread block.
template<bool LO>
__device__ void tconv64_body(const float* __restrict__ src, bf16_t* __restrict__ outh,
                             bf16_t* __restrict__ outl, int K, int N, int kt, int nt,
                             float4* t /* 64*16 float4 = 16KB */, int tid) {
    const int k0 = kt * 64, n0 = nt * 64;
#pragma unroll
    for (int p = 0; p < 4; ++p) {
        int row = p * 16 + (tid >> 4);
        int c = tid & 15;
        float4 v = *(const float4*)(src + (size_t)(k0 + row) * N + n0 + c * 4);
        t[row * 16 + (c ^ ((row >> 2) & 15))] = v;
    }
    __syncthreads();
    const int n = tid >> 2, b = tid & 3;
    const float* tf = (const float*)t;
    float v[16];
#pragma unroll
    for (int i = 0; i < 16; ++i) {
        int k = 16 * b + i;
        int f4 = k * 16 + ((n >> 2) ^ ((k >> 2) & 15));
        v[i] = tf[f4 * 4 + (n & 3)];
    }
    bf16x8 h0, h1;
#pragma unroll
    for (int i = 0; i < 8; ++i) { h0[i] = (bf16_t)v[i]; h1[i] = (bf16_t)v[8 + i]; }
    size_t oi = (size_t)(n0 + n) * K + k0 + 16 * b;
    *(bf16x8*)(outh + oi) = h0;
    *(bf16x8*)(outh + oi + 8) = h1;
    if constexpr (LO) {
        bf16x8 l0, l1;
#pragma unroll
        for (int i = 0; i < 8; ++i) {
            l0[i] = (bf16_t)(v[i] - (float)h0[i]);
            l1[i] = (bf16_t)(v[8 + i] - (float)h1[i]);
        }
        *(bf16x8*)(outl + oi) = l0;
        *(bf16x8*)(outl + oi + 8) = l1;
    }
}

// ---------------- prep_a: x hi/lo split + Wr1 transpose (gates router1 only) ----------------
#define NCVT2 2048
#define PREP_A_GRID (NCVT2 + 256)

__global__ __launch_bounds__(256) void prep_a_kernel(
    const float* __restrict__ x, const float* __restrict__ Wr1,
    bf16_t* __restrict__ xh, bf16_t* __restrict__ xl,
    bf16_t* __restrict__ Wr1h, bf16_t* __restrict__ Wr1l) {
    __shared__ float4 t[64 * 16];
    int b = blockIdx.x;
    if (b < NCVT2) {                     // x -> hi/lo bf16 split, 32B/lane
        size_t i = (size_t)b * 256 + threadIdx.x;
        const float4* x4 = (const float4*)x;
        float4 v0 = x4[2 * i], v1 = x4[2 * i + 1];
        float f[8] = {v0.x, v0.y, v0.z, v0.w, v1.x, v1.y, v1.z, v1.w};
        bf16x8 h, l;
#pragma unroll
        for (int j = 0; j < 8; ++j) { h[j] = (bf16_t)f[j]; l[j] = (bf16_t)(f[j] - (float)h[j]); }
        *(bf16x8*)(xh + i * 8) = h;
        *(bf16x8*)(xl + i * 8) = l;
        return;
    }
    b -= NCVT2;
    tconv64_body<true>(Wr1, Wr1h, Wr1l, DM, DM, b >> 4, b & 15, t, threadIdx.x);
}

// ---------------- GEMM body: C[M,N] = A[M,K] @ Bt[N,K]^T (+bias, opt gelu) ----------------
// Proven round-1/4 structure: 128x128 tile, BK template (32 or 64), 8 waves
// (2x4: wave tile 64x32), global_load_lds width-16 staging with XOR swizzle,
// 2-stage LDS double-buffer, one __syncthreads per K-step.
template<bool SPLIT, bool GATHER, bool GELU, bool SCATTER, bool OUTF32, int BK>
__device__ __forceinline__ void gemm_body(
    const bf16_t* __restrict__ A, const bf16_t* __restrict__ Alo,
    const bf16_t* __restrict__ Bt, const bf16_t* __restrict__ Btlo,
    const float* __restrict__ bias,
    float* __restrict__ outF, bf16_t* __restrict__ outB,
    const int* __restrict__ perm, const int* __restrict__ counts,
    int M, int N, int K, int bx, int by,
    bf16_t* As, bf16_t* Bs, bf16_t* Asl, bf16_t* Bsl) {
    constexpr int NCH = BK / 32;           // 32-k chunks per K-step
    constexpr int CH  = 128 * 32;          // elements per chunk (8KB)
    constexpr int BUF = NCH * CH;          // elements per K-step buffer

    int tile = 0, rb, cnt = M;
    const int* permT = nullptr;
    if constexpr (GATHER) {
        int xb = bx, t = 0, c = 0;
        while (t < NTILES) {
            c = counts[t];
            int nbk = (c + 127) >> 7;
            if (xb < nbk) break;
            xb -= nbk; ++t;
        }
        if (t == NTILES) return;          // beyond total routed blocks (uniform)
        tile = t;
        rb = xb * 128;
        cnt = c;
        permT = perm + tile * BATCH;
    } else {
        rb = bx * 128;
    }
    Bt   += (size_t)tile * K * N;
    if constexpr (SPLIT) Btlo += (size_t)tile * K * N;
    bias += (size_t)tile * N;

    const int lane = threadIdx.x & 63;
    const int wave = threadIdx.x >> 6;     // 0..7
    const int wm = wave & 1, wn = wave >> 1;   // 2 x 4 wave grid
    const int nb = by * 128;

    // staging source offsets (one 16B lane-load per matrix per 32-chunk)
    const int srow = lane >> 2;                       // 0..15 within wave's 16-row seg
    const int scol = ((lane & 3) ^ (srow & 3)) * 8;   // swizzled k-chunk (elements)
    const int row = wave * 16 + srow;                 // 0..127
    int arow;
    if constexpr (GATHER) {
        int pos = rb + row;
        if (pos > cnt - 1) pos = cnt - 1;
        arow = permT[pos];
    } else {
        arow = rb + row;
    }
    const size_t aoff = (size_t)arow * K + scol;
    const size_t boff = (size_t)(nb + row) * K + scol;

    f32x4 acc[4][2];
#pragma unroll
    for (int i = 0; i < 4; ++i)
#pragma unroll
        for (int j = 0; j < 2; ++j) acc[i][j] = (f32x4){0.f, 0.f, 0.f, 0.f};

    const int lr = lane & 15, lq = lane >> 4;
    const int rdoff = (lr * 4 + (lq ^ (lr & 3))) * 8;

    auto stage = [&](int k0, int buf) {
#pragma unroll
        for (int c = 0; c < NCH; ++c) {
            async_ld16(A  + aoff + k0 + c * 32, &As[buf * BUF + c * CH + wave * 512]);
            async_ld16(Bt + boff + k0 + c * 32, &Bs[buf * BUF + c * CH + wave * 512]);
            if constexpr (SPLIT) {
                async_ld16(Alo  + aoff + k0 + c * 32, &Asl[buf * BUF + c * CH + wave * 512]);
                async_ld16(Btlo + boff + k0 + c * 32, &Bsl[buf * BUF + c * CH + wave * 512]);
            }
        }
    };

    auto compute = [&](int cur) {
#pragma unroll
        for (int kk = 0; kk < NCH; ++kk) {
            const int base = cur * BUF + kk * CH;
            bf16x8 af[4], bfr[2], afl[4], bfl[2];
#pragma unroll
            for (int i = 0; i < 4; ++i) {
                af[i] = *(const bf16x8*)&As[base + (wm * 4 + i) * 512 + rdoff];
                if constexpr (SPLIT)
                    afl[i] = *(const bf16x8*)&Asl[base + (wm * 4 + i) * 512 + rdoff];
            }
#pragma unroll
            for (int j = 0; j < 2; ++j) {
                bfr[j] = *(const bf16x8*)&Bs[base + (wn * 2 + j) * 512 + rdoff];
                if constexpr (SPLIT)
                    bfl[j] = *(const bf16x8*)&Bsl[base + (wn * 2 + j) * 512 + rdoff];
            }
#pragma unroll
            for (int i = 0; i < 4; ++i)
#pragma unroll
                for (int j = 0; j < 2; ++j) {
                    acc[i][j] = mfma16(af[i], bfr[j], acc[i][j]);
                    if constexpr (SPLIT) {
                        // hi*lo cross terms; lo*lo ~1e-6, dropped
                        acc[i][j] = mfma16(af[i], bfl[j], acc[i][j]);
                        acc[i][j] = mfma16(afl[i], bfr[j], acc[i][j]);
                    }
                }
        }
    };

    stage(0, 0);
    int cur = 0;
    for (int k0 = 0; k0 < K; k0 += BK, cur ^= 1) {
        __syncthreads();                  // drains vmcnt: buf[cur] ready
        if (k0 + BK < K) stage(k0 + BK, cur ^ 1);
        compute(cur);
    }

    // epilogue: C row = (lane>>4)*4 + reg, col = lane&15 (m89/m91-verified)
#pragma unroll
    for (int i = 0; i < 4; ++i) {
#pragma unroll
        for (int j = 0; j < 2; ++j) {
#pragma unroll
            for (int r = 0; r < 4; ++r) {
                int m = wm * 64 + i * 16 + lq * 4 + r;
                int n = wn * 32 + j * 16 + lr;
                int pos = rb + m;
                if constexpr (GATHER) { if (pos >= cnt) continue; }
                int grow;
                if constexpr (SCATTER) grow = permT[pos];
                else                   grow = pos;
                int gn = nb + n;
                float v = acc[i][j][r] + bias[gn];
                if constexpr (GELU) v = gelu_exact(v);
                if constexpr (OUTF32) outF[(size_t)grow * N + gn] = v;
                else                  outB[(size_t)grow * N + gn] = (bf16_t)v;
            }
        }
    }
}

// ---------------- fused router1 + W1/W2/Wo transposes ----------------
// bid<256: router1 SPLIT GEMM blocks (spread across all CUs at dispatch start,
// BK=32 -> 64KB LDS -> 2 blocks/CU). bid>=256: 4224 transpose blocks, each
// running two proven 64x64 tconv tiles (one per 256-thread half) in the same
// 64KB LDS footprint. The latency-bound GEMM and latency-bound transposes
// co-reside per CU and fill each other's stall cycles. Stream order still
// guarantees W1t/W2t/Wot complete before e1/e2/outproj.
#define NTCONV_TILES (4096 + 4096 + 256)            // W1 + W2 + Wo
#define R1F_GRID (256 + NTCONV_TILES / 2)           // 4480

__global__ __launch_bounds__(512) void r1_fused_kernel(
    const bf16_t* __restrict__ xh, const bf16_t* __restrict__ xl,
    const bf16_t* __restrict__ Wr1h, const bf16_t* __restrict__ Wr1l,
    const float* __restrict__ br1, float* __restrict__ Hr,
    const float* __restrict__ W1, const float* __restrict__ W2,
    const float* __restrict__ Wo,
    bf16_t* __restrict__ W1t, bf16_t* __restrict__ W2t, bf16_t* __restrict__ Wot) {
    __shared__ __align__(16) bf16_t smem[32768];    // 64KB shared by both paths
    const int bid = blockIdx.x;
    if (bid < 256) {
        gemm_body<true, false, true, false, true, 32>(
            xh, xl, Wr1h, Wr1l, br1, Hr, nullptr, nullptr, nullptr,
            BATCH, DM, DM, bid & 31, bid >> 5,
            smem, smem + 8192, smem + 16384, smem + 24576);
        return;
    }
    const int tix = bid - 256;
    const int half = threadIdx.x >> 8;               // 0/1: two tiles per block
    const int tid = threadIdx.x & 255;
    float4* t = (float4*)smem + half * 1024;         // 16KB per half
    const int tile = tix * 2 + half;                 // 0..8447
    if (tile < 4096) {                               // W1: (1024k,2048n), 16kt x 32nt
        int mat = tile >> 9, r = tile & 511;
        size_t off = (size_t)mat * DM * DFF;
        tconv64_body<false>(W1 + off, W1t + off, nullptr, DM, DFF, r >> 5, r & 31, t, tid);
    } else if (tile < 8192) {                        // W2: (2048k,1024n), 32kt x 16nt
        int tt = tile - 4096;
        int mat = tt >> 9, r = tt & 511;
        size_t off = (size_t)mat * DM * DFF;
        tconv64_body<false>(W2 + off, W2t + off, nullptr, DFF, DM, r >> 4, r & 15, t, tid);
    } else {                                         // Wo: 16kt x 16nt
        int r = tile - 8192;
        tconv64_body<false>(Wo, Wot, nullptr, DM, DM, r >> 4, r & 15, t, tid);
    }
}

// ---------------- standalone GEMM wrapper (BK=64, round-4-proven) ----------------
template<bool SPLIT, bool GATHER, bool GELU, bool SCATTER, bool OUTF32>
__global__ __launch_bounds__(512) void gemm_kernel(
    const bf16_t* __restrict__ A, const bf16_t* __restrict__ Alo,
    const bf16_t* __restrict__ Bt, const bf16_t* __restrict__ Btlo,
    const float* __restrict__ bias,
    float* __restrict__ outF, bf16_t* __restrict__ outB,
    const int* __restrict__ perm, const int* __restrict__ counts,
    int M, int N, int K) {
    constexpr int E = 2 * 2 * 128 * 32;   // 16384 elements = 32KB per matrix
    __shared__ __align__(16) bf16_t As[E];
    __shared__ __align__(16) bf16_t Bs[E];
    __shared__ __align__(16) bf16_t Asl[SPLIT ? E : 8];
    __shared__ __align__(16) bf16_t Bsl[SPLIT ? E : 8];
    gemm_body<SPLIT, GATHER, GELU, SCATTER, OUTF32, 64>(
        A, Alo, Bt, Btlo, bias, outF, outB, perm, counts,
        M, N, K, blockIdx.x, blockIdx.y, As, Bs, Asl, Bsl);
}

// ---------------- router layer2 + argmax + routing lists ----------------
// (unchanged)
__global__ __launch_bounds__(256) void router2_kernel(
    const float* __restrict__ Hr, const float* __restrict__ Wr2, const float* __restrict__ br2,
    float* __restrict__ outLog, float* __restrict__ outIdx,
    int* __restrict__ counts, int* __restrict__ perm) {
    __shared__ float w2s[DM * 9];
    __shared__ int h[NTILES], base[NTILES];
    const int tid = threadIdx.x;
    if (tid < NTILES) h[tid] = 0;
    for (int e = tid; e < DM * 8; e += 256) {
        int k = e >> 3, j = e & 7;
        w2s[k * 9 + j] = Wr2[e];
    }
    __syncthreads();

    const int lane = tid & 63, wave = tid >> 6;
    const int sub = lane >> 4;
    const int lr16 = lane & 15;
    const int row = blockIdx.x * 16 + wave * 4 + sub;

    const float4* Hr4 = (const float4*)Hr;
    float acc[8];
#pragma unroll
    for (int j = 0; j < 8; ++j) acc[j] = 0.f;

#pragma unroll
    for (int i = 0; i < 16; ++i) {
        int f = lr16 + i * 16;
        float4 hv = Hr4[(size_t)row * 256 + f];
        float hx[4] = {hv.x, hv.y, hv.z, hv.w};
        int kbase = f * 4;
#pragma unroll
        for (int d = 0; d < 4; ++d) {
            float xv = hx[d];
            const float* w = &w2s[(kbase + d) * 9];
#pragma unroll
            for (int j = 0; j < 8; ++j) acc[j] += xv * w[j];
        }
    }
#pragma unroll
    for (int off = 8; off; off >>= 1)
#pragma unroll
        for (int j = 0; j < 8; ++j) acc[j] += __shfl_down(acc[j], off);

    int bi = 0, rank = 0;
    if (lr16 == 0) {
        float best = -1e30f;
        float lg[8];
#pragma unroll
        for (int j = 0; j < 8; ++j) {
            float v = (acc[j] + br2[j]) * 2.0f;   // /TEMPERATURE, T=0.5
            lg[j] = v;
            if (v > best) { best = v; bi = j; }   // strict > == first-max (jnp.argmax)
        }
        float4 lo = {lg[0], lg[1], lg[2], lg[3]};
        float4 hi = {lg[4], lg[5], lg[6], lg[7]};
        *(float4*)(outLog + (size_t)row * 8)     = lo;
        *(float4*)(outLog + (size_t)row * 8 + 4) = hi;
        outIdx[row] = (float)bi;
        rank = atomicAdd(&h[bi], 1);
    }
    __syncthreads();
    if (tid < NTILES && h[tid] > 0) base[tid] = atomicAdd(&counts[tid], h[tid]);
    __syncthreads();
    if (lr16 == 0) perm[bi * BATCH + base[bi] + rank] = row;
}

// ---------------- host launch ----------------
extern "C" void kernel_launch(void* const* d_in, const int* in_sizes, int n_in,
                              void* d_out, int out_size, void* d_ws, size_t ws_size,
                              hipStream_t stream) {
    const float* x   = (const float*)d_in[0];
    const float* Wr1 = (const float*)d_in[1];
    const float* br1 = (const float*)d_in[2];
    const float* Wr2 = (const float*)d_in[3];
    const float* br2 = (const float*)d_in[4];
    const float* W1  = (const float*)d_in[5];
    const float* b1  = (const float*)d_in[6];
    const float* W2  = (const float*)d_in[7];
    const float* b2  = (const float*)d_in[8];
    const float* Wo  = (const float*)d_in[9];
    const float* bo  = (const float*)d_in[10];

    char* ws = (char*)d_ws;
    size_t o = 0;
    auto carve = [&](size_t bytes) { char* p = ws + o; o = (o + bytes + 255) & ~(size_t)255; return p; };
    bf16_t* Wr1h = (bf16_t*)carve((size_t)DM * DM * 2);
    bf16_t* Wr1l = (bf16_t*)carve((size_t)DM * DM * 2);
    bf16_t* Wot  = (bf16_t*)carve((size_t)DM * DM * 2);
    bf16_t* W1t  = (bf16_t*)carve((size_t)NTILES * DM * DFF * 2);
    bf16_t* W2t  = (bf16_t*)carve((size_t)NTILES * DM * DFF * 2);
    bf16_t* xh   = (bf16_t*)carve((size_t)BATCH * DM * 2);
    bf16_t* xl   = (bf16_t*)carve((size_t)BATCH * DM * 2);
    bf16_t* H1   = (bf16_t*)carve((size_t)BATCH * DFF * 2);
    bf16_t* sel  = (bf16_t*)carve((size_t)BATCH * DM * 2);
    float*  Hr   = (float*)carve((size_t)BATCH * DM * 4);
    int*    counts = (int*)carve(NTILES * sizeof(int));
    int*    perm   = (int*)carve((size_t)NTILES * BATCH * sizeof(int));

    float* outMain = (float*)d_out;
    float* outIdx  = outMain + (size_t)BATCH * DM;
    float* outLog  = outIdx + BATCH;

    hipMemsetAsync(counts, 0, NTILES * sizeof(int), stream);

    // stage A: only what router1 needs (x split + Wr1 hi/lo transpose)
    prep_a_kernel<<<PREP_A_GRID, 256, 0, stream>>>(x, Wr1, xh, xl, Wr1h, Wr1l);

    // router layer 1 (hi/lo split GEMM) fused with W1/W2/Wo transposes:
    // transpose traffic fills the GEMM's latency stalls; results needed only
    // by later dispatches.
    r1_fused_kernel<<<R1F_GRID, 512, 0, stream>>>(xh, xl, Wr1h, Wr1l, br1, Hr,
                                                  W1, W2, Wo, W1t, W2t, Wot);

    router2_kernel<<<BATCH / 16, 256, 0, stream>>>(Hr, Wr2, br2, outLog, outIdx, counts, perm);

    // expert layer 1: H1[token] = gelu(x[token] @ W1[t] + b1[t]), gathered+scattered
    gemm_kernel<false, true, true, true, false><<<dim3(MAXXB, DFF / 128, 1), 512, 0, stream>>>(
        xh, nullptr, W1t, nullptr, b1, nullptr, H1, perm, counts, BATCH, DFF, DM);

    // expert layer 2: sel[token] = H1[token] @ W2[t] + b2[t]
    gemm_kernel<false, true, false, true, false><<<dim3(MAXXB, DM / 128, 1), 512, 0, stream>>>(
        H1, nullptr, W2t, nullptr, b2, nullptr, sel, perm, counts, BATCH, DM, DFF);

    // output projection: out = sel @ Wo + bo
    gemm_kernel<false, false, false, false, true><<<dim3(BATCH / 128, DM / 128, 1), 512, 0, stream>>>(
        sel, nullptr, Wot, nullptr, bo, outMain, nullptr, nullptr, nullptr, BATCH, DM, DM);
}